// Round 10
// baseline (64.308 us; speedup 1.0000x reference)
//
#include <hip/hip_runtime.h>
#include <hip/hip_bf16.h>

typedef float f2 __attribute__((ext_vector_type(2)));

// ---------------- helpers ----------------

// swizzle for 4096-amp f2 LDS tile: XOR low 4 bits with bits 4-7 (bijective)
#define SWZA(i) ((i) ^ (((i) >> 4) & 15))

// complex 2x2 gate on an amplitude pair; u = {u00r,u00i,u01r,u01i,u10r,u10i,u11r,u11i}
__device__ __forceinline__ void gate1q(f2& a0, f2& a1, const float* u) {
    f2 s0 = { -a0.y, a0.x };
    f2 s1 = { -a1.y, a1.x };
    f2 n0 = u[0]*a0 + u[1]*s0 + u[2]*a1 + u[3]*s1;
    f2 n1 = u[4]*a0 + u[5]*s0 + u[6]*a1 + u[7]*s1;
    a0 = n0; a1 = n1;
}

// RX on the (a0,a1) pair: n0 = c*a0 - i*s*a1 ; n1 = -i*s*a0 + c*a1
__device__ __forceinline__ void crx_pair(f2& a0, f2& a1, float c, float s) {
    f2 t0 = { a0.y, -a0.x };
    f2 t1 = { a1.y, -a1.x };
    f2 n0 = c*a0 + s*t1;
    f2 n1 = c*a1 + s*t0;
    a0 = n0; a1 = n1;
}

// plain 1q gate over W-amp window, target bit K
template<int K, int W>
__device__ __forceinline__ void apply1q_win(f2* a, const float* u) {
    #pragma unroll
    for (int m = 0; m < W / 2; ++m) {
        const int j0 = ((m >> K) << (K + 1)) | (m & ((1 << K) - 1));
        gate1q(a[j0], a[j0 | (1 << K)], u);
    }
}

// merged (U_q then CRX(q-1,q)) : control-selected 2x2. u16 = {U | RX*U}
template<int K, int KC, int W>
__device__ __forceinline__ void apply1q_mg(f2* a, const float* u16) {
    #pragma unroll
    for (int m = 0; m < W / 2; ++m) {
        const int j0 = ((m >> K) << (K + 1)) | (m & ((1 << K) - 1));
        const float* uu = u16 + (((j0 >> KC) & 1) << 3);
        gate1q(a[j0], a[j0 | (1 << K)], uu);
    }
}

__device__ __forceinline__ void loadU16(const float* __restrict__ src, float* u) {
    #pragma unroll
    for (int k = 0; k < 16; ++k) u[k] = src[k];
}

// ---------------- kernel 1: adaptive pool ----------------
__global__ __launch_bounds__(256) void pool_kernel(const float* __restrict__ x,
                                                   float* __restrict__ p) {
    int blk = blockIdx.x;            // b*32 + j
    int b = blk >> 5, j = blk & 31;
    int c = j >> 4, dd = (j >> 2) & 3, hh = j & 3;
    const float4* xb = (const float4*)(x + (((size_t)(b * 2 + c) * 16 + dd * 4) << 12)
                                         + (size_t)hh * 1024);
    int tid = threadIdx.x;
    float sum = 0.f;
    #pragma unroll
    for (int k = 0; k < 4; ++k) {
        int f = k * 256 + tid;
        int r = f >> 4, col = f & 15;
        int off = (r >> 4) * 1024 + (r & 15) * 16 + col;
        float4 v = xb[off];
        sum += v.x + v.y + v.z + v.w;
    }
    #pragma unroll
    for (int o = 1; o < 64; o <<= 1) sum += __shfl_xor(sum, o);
    __shared__ float red[4];
    if ((tid & 63) == 0) red[tid >> 6] = sum;
    __syncthreads();
    if (tid == 0) p[blk] = (red[0] + red[1] + red[2] + red[3]) * (1.0f / 4096.0f);
}

// ---------------- kernel 2: EVERYTHING per batch in one block -----------------------
// grid = 128 (one block per batch), 256 threads, ~68 KB LDS.
// prep -> right chains (LDS) -> layer0 passA -> layer1 left gates (4 factors, in LDS)
// -> rank-4 expansion + CRX(15,0) + EV reduce (WHT) -> head + log_softmax -> out.
__global__ __launch_bounds__(256) void qall(const float* __restrict__ p,
                                            const float* __restrict__ cw,
                                            const float* __restrict__ cb,
                                            const float* __restrict__ rot1,
                                            const float* __restrict__ crx1,
                                            const float* __restrict__ rot2,
                                            const float* __restrict__ crx2,
                                            const float* __restrict__ fcw,
                                            const float* __restrict__ fcb,
                                            float* __restrict__ out) {
    __shared__ f2 lds[8192];
    __shared__ float pp[32];
    __shared__ float uL0[12][16];   // layer-0 merged U0..U11
    __shared__ float uB0[4][16];    // layer-0 merged U12..U15
    __shared__ float uL1[11][16];   // layer-1 merged U0..U10
    __shared__ float uR1[5][16];    // layer-1 merged U11..U15
    __shared__ float cs15l0[2];     // layer-0 CRX(15,0) c,s
    __shared__ float cs15l1[2];     // layer-1 CRX(15,0) c,s
    __shared__ float rloc[2][4][64];   // right chains [bsel][k][m*2 + ri]
    __shared__ float redP[4][7];    // per wave: slot0 = total, 1+q = lane 2^q (q=0..5)
    __shared__ float redQ[4][8];    // per wave: P8,P9,P10,S0..S4
    __shared__ float evf[16];
    __shared__ float lgf[16];
    int b = blockIdx.x, tid = threadIdx.x;

    if (tid < 32) pp[tid] = p[b * 32 + tid];
    __syncthreads();
    if (tid < 16) {
        int q = tid;
        float f = cb[q];
        #pragma unroll
        for (int jj = 0; jj < 32; ++jj) f += pp[jj] * cw[q * 32 + jj];
        float cr = cosf(0.5f * f), sr = sinf(0.5f * f);
        #pragma unroll
        for (int l = 0; l < 2; ++l) {
            const float* rw = (l == 0 ? rot1 : rot2) + q * 3;
            float phi = rw[0], th = rw[1], om = rw[2];
            float ct = cosf(0.5f * th), st = sinf(0.5f * th);
            float aa = 0.5f * (phi + om), dd = 0.5f * (phi - om);
            float ca = cosf(aa), sa = sinf(aa), cd = cosf(dd), sd = sinf(dd);
            float R00r =  ct * ca, R00i = -ct * sa;
            float R01r = -st * cd, R01i = -st * sd;
            float R10r =  st * cd, R10i = -st * sd;
            float R11r =  ct * ca, R11i =  ct * sa;
            float u0 = cr * R00r + sr * R01i;
            float u1 = cr * R00i - sr * R01r;
            float u2 = cr * R01r + sr * R00i;
            float u3 = cr * R01i - sr * R00r;
            float u4 = cr * R10r + sr * R11i;
            float u5 = cr * R10i - sr * R11r;
            float u6 = cr * R11r + sr * R10i;
            float u7 = cr * R11i - sr * R10r;
            float g[16];
            g[0] = u0; g[1] = u1; g[2] = u2; g[3] = u3;
            g[4] = u4; g[5] = u5; g[6] = u6; g[7] = u7;
            if (q >= 1) {
                float thc = (l == 0 ? crx1 : crx2)[q - 1];
                float c2 = cosf(0.5f * thc), s2 = sinf(0.5f * thc);
                g[8]  = c2*u0 + s2*u5;  g[9]  = c2*u1 - s2*u4;
                g[10] = c2*u2 + s2*u7;  g[11] = c2*u3 - s2*u6;
                g[12] = c2*u4 + s2*u1;  g[13] = c2*u5 - s2*u0;
                g[14] = c2*u6 + s2*u3;  g[15] = c2*u7 - s2*u2;
            } else {
                #pragma unroll
                for (int k = 0; k < 8; ++k) g[8 + k] = g[k];
            }
            float* s = (l == 0) ? ((q < 12) ? uL0[q] : uB0[q - 12])
                                : ((q < 11) ? uL1[q] : uR1[q - 11]);
            #pragma unroll
            for (int k = 0; k < 16; ++k) s[k] = g[k];
            if (q == 15) {
                float th2 = (l == 0 ? crx1 : crx2)[15];
                float* cd2 = (l == 0) ? cs15l0 : cs15l1;
                cd2[0] = cosf(0.5f * th2);
                cd2[1] = sinf(0.5f * th2);
            }
        }
    }
    __syncthreads();

    // ---- right chains: 8 threads, one per (j, c, bsel) -> rloc (LDS) ----
    if (tid >= 32 && tid < 40) {
        int idx = tid - 32;
        int j = idx & 1, c = (idx >> 1) & 1, bsel = (idx >> 2) & 1;
        f2 w[32];
        #pragma unroll
        for (int m = 0; m < 32; ++m) w[m] = f2{0.f, 0.f};
        w[j] = f2{1.f, 0.f};
        apply1q_mg<1, 0, 32>(w, uB0[0]);
        apply1q_mg<2, 1, 32>(w, uB0[1]);
        apply1q_mg<3, 2, 32>(w, uB0[2]);
        apply1q_mg<4, 3, 32>(w, uB0[3]);
        #pragma unroll
        for (int m = 0; m < 32; ++m)
            if (((m >> 4) & 1) != c) w[m] = f2{0.f, 0.f};
        #pragma unroll
        for (int mm = 0; mm < 32; mm += 2)
            gate1q(w[mm], w[mm + 1], uR1[0] + (bsel << 3));
        apply1q_mg<1, 0, 32>(w, uR1[1]);
        apply1q_mg<2, 1, 32>(w, uR1[2]);
        apply1q_mg<3, 2, 32>(w, uR1[3]);
        apply1q_mg<4, 3, 32>(w, uR1[4]);
        int k = (c << 1) | j;
        #pragma unroll
        for (int m = 0; m < 32; ++m) {
            rloc[bsel][k][2 * m]     = w[m].x;
            rloc[bsel][k][2 * m + 1] = w[m].y;
        }
    }

    // ---- layer-0 pass A on e_0 (bits 0-11, merged gates U0..U11) -> lds[0..4095] ---
    #pragma unroll
    for (int j = 0; j < 16; ++j) lds[SWZA(j * 256 + tid)] = f2{0.f, 0.f};
    if (tid == 0) lds[SWZA(0)] = f2{1.f, 0.f};
    __syncthreads();

    {
        f2 a[16];
        // SR1: bits 0..3
        #pragma unroll
        for (int j = 0; j < 16; ++j) a[j] = lds[SWZA((tid << 4) | j)];
        apply1q_win<0, 16>(a, uL0[0]);
        apply1q_mg<1, 0, 16>(a, uL0[1]);
        apply1q_mg<2, 1, 16>(a, uL0[2]);
        apply1q_mg<3, 2, 16>(a, uL0[3]);
        #pragma unroll
        for (int j = 0; j < 16; ++j) lds[SWZA((tid << 4) | j)] = a[j];
        __syncthreads();
        // SR2: bits 3..6
        int lo = tid & 7, hi = (tid >> 3) << 7;
        #pragma unroll
        for (int j = 0; j < 16; ++j) a[j] = lds[SWZA(lo | (j << 3) | hi)];
        apply1q_mg<1, 0, 16>(a, uL0[4]);
        apply1q_mg<2, 1, 16>(a, uL0[5]);
        apply1q_mg<3, 2, 16>(a, uL0[6]);
        #pragma unroll
        for (int j = 0; j < 16; ++j) lds[SWZA(lo | (j << 3) | hi)] = a[j];
        __syncthreads();
        // SR3: bits 6..9
        int lo2 = tid & 63, hi2 = (tid >> 6) << 10;
        #pragma unroll
        for (int j = 0; j < 16; ++j) a[j] = lds[SWZA(lo2 | (j << 6) | hi2)];
        apply1q_mg<1, 0, 16>(a, uL0[7]);
        apply1q_mg<2, 1, 16>(a, uL0[8]);
        apply1q_mg<3, 2, 16>(a, uL0[9]);
        #pragma unroll
        for (int j = 0; j < 16; ++j) lds[SWZA(lo2 | (j << 6) | hi2)] = a[j];
        __syncthreads();
        // SR4: bits 8..11
        #pragma unroll
        for (int j = 0; j < 16; ++j) a[j] = lds[SWZA(tid | (j << 8))];
        apply1q_mg<2, 1, 16>(a, uL0[10]);
        apply1q_mg<3, 2, 16>(a, uL0[11]);
        #pragma unroll
        for (int j = 0; j < 16; ++j) lds[SWZA(tid | (j << 8))] = a[j];
        __syncthreads();
    }

    // ---- layer-1 left gates G0..G10 on 4 left factors (vv = tid>>7 = RX0 variant) ---
    {
        float g[16];
        f2 a[32];
        // R1: window bits 0-4 ; thread = (vv, j, outer = t bits 5-10)
        {
            int vv = tid >> 7, j = (tid >> 6) & 1, outer = tid & 63;
            int base = (j << 11) | (outer << 5);
            #pragma unroll
            for (int w = 0; w < 32; ++w) a[w] = lds[SWZA(base | w)];   // read u (half0)
            __syncthreads();   // all reads of half0 done before half0 is overwritten
            if (vv) {          // v = RX0(theta15_L0) u : bit 0 = window bit 0
                float c = cs15l0[0], s = cs15l0[1];
                #pragma unroll
                for (int w = 0; w < 32; w += 2) crx_pair(a[w], a[w + 1], c, s);
            }
            loadU16(uL1[0], g);  apply1q_win<0, 32>(a, g);      // G0
            loadU16(uL1[1], g);  apply1q_mg<1, 0, 32>(a, g);    // G1
            loadU16(uL1[2], g);  apply1q_mg<2, 1, 32>(a, g);    // G2
            loadU16(uL1[3], g);  apply1q_mg<3, 2, 32>(a, g);    // G3
            loadU16(uL1[4], g);  apply1q_mg<4, 3, 32>(a, g);    // G4
            #pragma unroll
            for (int w = 0; w < 32; ++w) lds[(vv << 12) | SWZA(base | w)] = a[w];
        }
        __syncthreads();
        // R2: window bits 4-8 ; thread = (vv, j, b910, b03)
        {
            int vv = tid >> 7, j = (tid >> 6) & 1, b910 = (tid >> 4) & 3, b03 = tid & 15;
            int base = (j << 11) | (b910 << 9) | b03;
            #pragma unroll
            for (int w = 0; w < 32; ++w) a[w] = lds[(vv << 12) | SWZA(base | (w << 4))];
            loadU16(uL1[5], g);  apply1q_mg<1, 0, 32>(a, g);    // G5
            loadU16(uL1[6], g);  apply1q_mg<2, 1, 32>(a, g);    // G6
            loadU16(uL1[7], g);  apply1q_mg<3, 2, 32>(a, g);    // G7
            loadU16(uL1[8], g);  apply1q_mg<4, 3, 32>(a, g);    // G8
            #pragma unroll
            for (int w = 0; w < 32; ++w) lds[(vv << 12) | SWZA(base | (w << 4))] = a[w];
        }
        __syncthreads();
        // R3: window bits 6-10 ; thread = (vv, j, b05) ; write back to LDS
        {
            int vv = tid >> 7, j = (tid >> 6) & 1, b05 = tid & 63;
            int base = (j << 11) | b05;
            #pragma unroll
            for (int w = 0; w < 32; ++w) a[w] = lds[(vv << 12) | SWZA(base | (w << 6))];
            loadU16(uL1[9], g);   apply1q_mg<3, 2, 32>(a, g);   // G9
            loadU16(uL1[10], g);  apply1q_mg<4, 3, 32>(a, g);   // G10
            #pragma unroll
            for (int w = 0; w < 32; ++w) lds[(vv << 12) | SWZA(base | (w << 6))] = a[w];
        }
        __syncthreads();
    }

    // ---- rank-4 expansion + layer-1 CRX(15,0) + EV accumulation ----
    float Ptot = 0.f, P8 = 0.f, P9 = 0.f, P10 = 0.f;
    float S0 = 0.f, S1 = 0.f, S2 = 0.f, S3 = 0.f, S4 = 0.f;
    float c15 = cs15l1[0], s15 = cs15l1[1];
    for (int pit = 0; pit < 8; ++pit) {
        int t = (pit << 8) | tid;
        int bsel = (pit >> 2) & 1;           // t bit 10
        f2 A[4], sA[4];
        #pragma unroll
        for (int k = 0; k < 4; ++k) {
            A[k] = lds[((k >> 1) << 12) | SWZA(((k & 1) << 11) | t)];
            sA[k] = f2{ -A[k].y, A[k].x };
        }
        const float* rb = &rloc[bsel][0][0];   // [k][2m]
        f2 a[32];
        #pragma unroll
        for (int m = 0; m < 32; ++m) {
            f2 ac = rb[0 * 64 + 2 * m] * A[0] + rb[0 * 64 + 2 * m + 1] * sA[0];
            ac   += rb[1 * 64 + 2 * m] * A[1] + rb[1 * 64 + 2 * m + 1] * sA[1];
            ac   += rb[2 * 64 + 2 * m] * A[2] + rb[2 * 64 + 2 * m + 1] * sA[2];
            ac   += rb[3 * 64 + 2 * m] * A[3] + rb[3 * 64 + 2 * m + 1] * sA[3];
            a[m] = ac;
        }
        // layer-1 CRX(15,0): control = m bit 4, target = t bit 0 = lane bit 0
        #pragma unroll
        for (int m = 16; m < 32; ++m) {
            float pr = __shfl_xor(a[m].x, 1);
            float pi = __shfl_xor(a[m].y, 1);
            float nr = c15 * a[m].x + s15 * pi;
            float ni = c15 * a[m].y - s15 * pr;
            a[m].x = nr; a[m].y = ni;
        }
        float P = 0.f, s0 = 0.f, s1 = 0.f, s2 = 0.f, s3 = 0.f, s4 = 0.f;
        #pragma unroll
        for (int m = 0; m < 32; ++m) {
            float pr = a[m].x * a[m].x + a[m].y * a[m].y;
            P += pr;
            s0 += (m & 1)  ? -pr : pr;
            s1 += (m & 2)  ? -pr : pr;
            s2 += (m & 4)  ? -pr : pr;
            s3 += (m & 8)  ? -pr : pr;
            s4 += (m & 16) ? -pr : pr;
        }
        Ptot += P;
        P8  += (pit & 1) ? -P : P;           // t bit 8
        P9  += (pit & 2) ? -P : P;           // t bit 9
        P10 += (pit & 4) ? -P : P;           // t bit 10
        S0 += s0; S1 += s1; S2 += s2; S3 += s3; S4 += s4;
    }

    // ---- wave reductions: WHT for Ptot (t bits 0-5), plain sums for the rest ----
    int lane = tid & 63, wave = tid >> 6;
    #pragma unroll
    for (int o = 1; o < 64; o <<= 1) {
        float tP = __shfl_xor(Ptot, o);
        Ptot = (lane & o) ? (tP - Ptot) : (Ptot + tP);
        P8  += __shfl_xor(P8, o);
        P9  += __shfl_xor(P9, o);
        P10 += __shfl_xor(P10, o);
        S0  += __shfl_xor(S0, o);
        S1  += __shfl_xor(S1, o);
        S2  += __shfl_xor(S2, o);
        S3  += __shfl_xor(S3, o);
        S4  += __shfl_xor(S4, o);
    }
    if ((lane & (lane - 1)) == 0) {       // lanes 0,1,2,4,8,16,32
        int slot = (lane == 0) ? 0 : (31 - __clz((unsigned)lane)) + 1;  // 1..6
        redP[wave][slot] = Ptot;
    }
    if (lane == 0) {
        redQ[wave][0] = P8;  redQ[wave][1] = P9;  redQ[wave][2] = P10;
        redQ[wave][3] = S0;  redQ[wave][4] = S1;  redQ[wave][5] = S2;
        redQ[wave][6] = S3;  redQ[wave][7] = S4;
    }
    __syncthreads();
    if (tid < 16) {
        int q = tid;
        float v;
        if (q < 6)       v = redP[0][1+q] + redP[1][1+q] + redP[2][1+q] + redP[3][1+q];
        else if (q == 6) v = redP[0][0] - redP[1][0] + redP[2][0] - redP[3][0]; // t6 = wave b0
        else if (q == 7) v = redP[0][0] + redP[1][0] - redP[2][0] - redP[3][0]; // t7 = wave b1
        else             v = redQ[0][q-8] + redQ[1][q-8] + redQ[2][q-8] + redQ[3][q-8];
        evf[q] = v;
    }
    __syncthreads();

    // ---- head: logits + log_softmax ----
    if (tid < 16) {
        int c = tid;
        float v = fcb[c];
        #pragma unroll
        for (int q = 0; q < 16; ++q) v += evf[q] * fcw[c * 16 + q];
        lgf[c] = v;
    }
    __syncthreads();
    if (tid < 16) {
        float mx = -1e30f;
        #pragma unroll
        for (int c2 = 0; c2 < 16; ++c2) mx = fmaxf(mx, lgf[c2]);
        float se = 0.f;
        #pragma unroll
        for (int c2 = 0; c2 < 16; ++c2) se += expf(lgf[c2] - mx);
        out[b * 16 + tid] = lgf[tid] - (mx + logf(se));
    }
}

// ---------------- launch ----------------
extern "C" void kernel_launch(void* const* d_in, const int* in_sizes, int n_in,
                              void* d_out, int out_size, void* d_ws, size_t ws_size,
                              hipStream_t stream) {
    const float* x    = (const float*)d_in[0];
    const float* cw   = (const float*)d_in[1];
    const float* cb   = (const float*)d_in[2];
    const float* rot1 = (const float*)d_in[3];
    const float* crx1 = (const float*)d_in[4];
    const float* rot2 = (const float*)d_in[5];
    const float* crx2 = (const float*)d_in[6];
    const float* fcw  = (const float*)d_in[7];
    const float* fcb  = (const float*)d_in[8];

    float* p = (float*)d_ws;   // 4096 floats

    pool_kernel<<<4096, 256, 0, stream>>>(x, p);
    qall<<<128, 256, 0, stream>>>(p, cw, cb, rot1, crx1, rot2, crx2,
                                  fcw, fcb, (float*)d_out);
}